// Round 4
// baseline (656.595 us; speedup 1.0000x reference)
//
#include <hip/hip_runtime.h>
#include <hip/hip_bf16.h>
#include <stdint.h>

#define D_IN   4096
#define D_OUT  4096
#define M_ROWS 8192          // B*S = 4*2048
#define SCALING 2.0f         // ALPHA/R = 16/8

typedef __attribute__((ext_vector_type(4))) float f32x4;
typedef __attribute__((ext_vector_type(4))) int   i32x4;
typedef __attribute__((ext_vector_type(8))) short s16x8;

__device__ __forceinline__ unsigned short f2bf_bits(float f) {
  __hip_bfloat16 h = __float2bfloat16(f);
  unsigned short b;
  __builtin_memcpy(&b, &h, 2);
  return b;
}
__device__ __forceinline__ float rbf(float f) {  // round to bf16, back to float
  return __bfloat162float(__float2bfloat16(f));
}

__device__ __forceinline__ void gload16(const void* g, void* l) {
  __builtin_amdgcn_global_load_lds(
      (const __attribute__((address_space(1))) unsigned int*)g,
      (__attribute__((address_space(3))) unsigned int*)l, 16, 0, 0);
}

// ---------------------------------------------------------------------------
// Kernel 1: NF4 dequant + transpose.  qweight arrives as INT32 (harness
// contract: integer inputs -> const int*).  Wt[n][k] = bf16(tbl[q[k][n]+8] *
// bf16(scale[k/128][n])).  64x64 tiles through LDS.
// ---------------------------------------------------------------------------
__global__ __launch_bounds__(256) void k_dequant(const int* __restrict__ q,
                                                 const float* __restrict__ scale,
                                                 unsigned short* __restrict__ wt) {
  __shared__ __align__(16) unsigned short tile[64][72];   // +pad
  __shared__ float stbl[16];
  const int t = threadIdx.x;
  const int k0 = blockIdx.x * 64;
  const int n0 = blockIdx.y * 64;
  const int g = k0 >> 7;                    // group index, constant per tile

  if (t < 16) {
    const float raw[16] = {-1.0f,-0.6962f,-0.5251f,-0.3949f,-0.2844f,-0.1848f,-0.0911f,0.0f,
                           0.0796f,0.1609f,0.2461f,0.3379f,0.4407f,0.5626f,0.723f,1.0f};
    stbl[t] = rbf(raw[t]);
  }
  __syncthreads();

  const int kr = t >> 2;                    // 0..63 row within K
  const int ns = (t & 3) << 4;              // 0,16,32,48 col seg within N
  const int* qp = q + (size_t)(k0 + kr) * D_OUT + n0 + ns;
  i32x4 qv[4];
#pragma unroll
  for (int i = 0; i < 4; ++i) qv[i] = reinterpret_cast<const i32x4*>(qp)[i];
  const float* sp = scale + (size_t)g * D_OUT + n0 + ns;
  float sv[16];
#pragma unroll
  for (int i = 0; i < 4; ++i) {
    f32x4 s4 = reinterpret_cast<const f32x4*>(sp)[i];
#pragma unroll
    for (int j = 0; j < 4; ++j) sv[i*4 + j] = s4[j];
  }
#pragma unroll
  for (int i = 0; i < 16; ++i) {
    int b = qv[i >> 2][i & 3];              // in [-8, 7]
    float w = stbl[b + 8] * rbf(sv[i]);
    tile[ns + i][kr] = f2bf_bits(w);
  }
  __syncthreads();

  const int nr = t >> 2;
  const int ks = (t & 3) << 4;
  uint4 v0 = *reinterpret_cast<const uint4*>(&tile[nr][ks]);
  uint4 v1 = *reinterpret_cast<const uint4*>(&tile[nr][ks + 8]);
  unsigned short* dst = wt + (size_t)(n0 + nr) * D_IN + k0 + ks;
  reinterpret_cast<uint4*>(dst)[0] = v0;
  reinterpret_cast<uint4*>(dst + 8)[0] = v1;
}

// ---------------------------------------------------------------------------
// Kernel 2: xb = bf16(x), hidden = x @ lora_a (fp32).
// ---------------------------------------------------------------------------
__global__ __launch_bounds__(256) void k_cast_hidden(const float* __restrict__ x,
                                                     const float* __restrict__ la,
                                                     unsigned short* __restrict__ xb,
                                                     float* __restrict__ hidden) {
  const int lane = threadIdx.x & 63;
  const int w = threadIdx.x >> 6;
  const int m0 = blockIdx.x * 16 + w * 4;
  float h[4][8];
#pragma unroll
  for (int i = 0; i < 4; ++i)
#pragma unroll
    for (int r = 0; r < 8; ++r) h[i][r] = 0.f;

  for (int kc = 0; kc < D_IN; kc += 256) {
    const int kb = kc + lane * 4;
    f32x4 a4[8];
    const f32x4* lap = reinterpret_cast<const f32x4*>(la + (size_t)kb * 8);
#pragma unroll
    for (int i = 0; i < 8; ++i) a4[i] = lap[i];
#pragma unroll
    for (int i = 0; i < 4; ++i) {
      const size_t off = (size_t)(m0 + i) * D_IN + kb;
      f32x4 xv = *reinterpret_cast<const f32x4*>(x + off);
      ushort4 pk;
      pk.x = f2bf_bits(xv[0]); pk.y = f2bf_bits(xv[1]);
      pk.z = f2bf_bits(xv[2]); pk.w = f2bf_bits(xv[3]);
      *reinterpret_cast<ushort4*>(xb + off) = pk;
#pragma unroll
      for (int kk = 0; kk < 4; ++kk) {
        float xvk = xv[kk];
#pragma unroll
        for (int r = 0; r < 8; ++r) h[i][r] += xvk * a4[kk*2 + (r >> 2)][r & 3];
      }
    }
  }
#pragma unroll
  for (int i = 0; i < 4; ++i) {
#pragma unroll
    for (int r = 0; r < 8; ++r) {
      float v = h[i][r];
#pragma unroll
      for (int off = 32; off > 0; off >>= 1) v += __shfl_xor(v, off, 64);
      if (lane == 0) hidden[(size_t)(m0 + i) * 8 + r] = v;
    }
  }
}

// ---------------------------------------------------------------------------
// Kernel 3: GEMM  out[m][n] = float(bf16(bf16(acc) + bf16(bias))) + 2*hidden.lora_b
// 128x128 tile, BK=64, 4 waves (2x2), mfma_f32_16x16x32_bf16, global_load_lds
// width-16 staging, both-sides XOR swizzle (rule #21), m97 2-barrier structure.
// (Proven output-equivalent to the reg-staged linear variant in rounds 2/3.)
// ---------------------------------------------------------------------------
#define TM 128
#define TN 128
#define TK 64
#define KTILES (D_IN / TK)

__global__ __launch_bounds__(256) void k_gemm(const unsigned short* __restrict__ A,   // xb [M][K]
                                              const unsigned short* __restrict__ Bt,  // Wt [N][K]
                                              const float* __restrict__ bias,
                                              const float* __restrict__ hidden,       // [M][8]
                                              const float* __restrict__ lorab,        // [8][N]
                                              float* __restrict__ out) {
  __shared__ __align__(16) unsigned short As[TM * TK];  // 16 KB, physically swizzled
  __shared__ __align__(16) unsigned short Bs[TN * TK];  // 16 KB
  const int tid  = threadIdx.x;
  const int lane = tid & 63;
  const int w    = tid >> 6;
  const int wm   = w >> 1, wn = w & 1;

  // T1: bijective XCD swizzle (gridDim 2048 % 8 == 0)
  const int per = gridDim.x >> 3;
  const int s   = (blockIdx.x & 7) * per + (blockIdx.x >> 3);
  const int tm  = s >> 5;            // N/TN = 32
  const int tn  = s & 31;
  const int m0  = tm * TM, n0 = tn * TN;

  // --- staging addressing (linear LDS dest, pre-swizzled global source) ---
  const int srow = lane >> 3;                         // row within 8-row chunk
  const int scol = (((lane & 7) ^ srow) << 4);        // source byte col (XOR pre-applied)
  const char* Ab = reinterpret_cast<const char*>(A);
  const char* Bb = reinterpret_cast<const char*>(Bt);
  char* AsB = reinterpret_cast<char*>(As);
  char* BsB = reinterpret_cast<char*>(Bs);
  size_t ga[4], gb[4];
  char *ldA[4], *ldB[4];
#pragma unroll
  for (int i = 0; i < 4; ++i) {
    const int chunk = w + 4 * i;                      // 16 chunks of 1KB
    const int row = chunk * 8 + srow;
    ga[i]  = (size_t)(m0 + row) * (D_IN * 2) + scol;
    gb[i]  = (size_t)(n0 + row) * (D_IN * 2) + scol;
    ldA[i] = AsB + chunk * 1024 + lane * 16;
    ldB[i] = BsB + chunk * 1024 + lane * 16;
  }

  // --- fragment read offsets (swizzled) ---
  const int fr  = lane & 15;
  const int swz = (lane & 7) << 4;
  const int kp  = (lane >> 4) << 4;
  int aoff[2][4], boff[2][4];
#pragma unroll
  for (int kk = 0; kk < 2; ++kk) {
    const int colp = ((kk << 6) | kp) ^ swz;
#pragma unroll
    for (int i = 0; i < 4; ++i) {
      aoff[kk][i] = (wm * 64 + i * 16 + fr) * 128 + colp;
      boff[kk][i] = (wn * 64 + i * 16 + fr) * 128 + colp;
    }
  }

  f32x4 acc[4][4] = {};

  for (int kt = 0; kt < KTILES; ++kt) {
#pragma unroll
    for (int i = 0; i < 4; ++i) gload16(Ab + ga[i], ldA[i]);
#pragma unroll
    for (int i = 0; i < 4; ++i) gload16(Bb + gb[i], ldB[i]);
#pragma unroll
    for (int i = 0; i < 4; ++i) { ga[i] += TK * 2; gb[i] += TK * 2; }
    __syncthreads();
#pragma unroll
    for (int kk = 0; kk < 2; ++kk) {
      s16x8 af[4], bf[4];
#pragma unroll
      for (int i = 0; i < 4; ++i) af[i] = *reinterpret_cast<const s16x8*>(AsB + aoff[kk][i]);
#pragma unroll
      for (int i = 0; i < 4; ++i) bf[i] = *reinterpret_cast<const s16x8*>(BsB + boff[kk][i]);
#pragma unroll
      for (int mi = 0; mi < 4; ++mi)
#pragma unroll
        for (int ni = 0; ni < 4; ++ni)
          acc[mi][ni] = __builtin_amdgcn_mfma_f32_16x16x32_bf16(af[mi], bf[ni], acc[mi][ni], 0, 0, 0);
    }
    __syncthreads();
  }

  // --- epilogue: stage hidden[128][8], lora_b[8][128], bias[128] in LDS ---
  float* eL = reinterpret_cast<float*>(As);
  {
    const int r0 = tid >> 1, c0 = (tid & 1) * 4;
    *reinterpret_cast<f32x4*>(&eL[r0 * 8 + c0]) =
        *reinterpret_cast<const f32x4*>(&hidden[(size_t)(m0 + r0) * 8 + c0]);
    const int rr = tid >> 5, cc = (tid & 31) * 4;
    *reinterpret_cast<f32x4*>(&eL[1024 + rr * 128 + cc]) =
        *reinterpret_cast<const f32x4*>(&lorab[(size_t)rr * D_OUT + n0 + cc]);
    if (tid < 32)
      *reinterpret_cast<f32x4*>(&eL[2048 + tid * 4]) =
          *reinterpret_cast<const f32x4*>(&bias[n0 + tid * 4]);
  }
  __syncthreads();

  float lbc[4][8], bcol[4];
#pragma unroll
  for (int ni = 0; ni < 4; ++ni) {
    const int col = wn * 64 + ni * 16 + fr;
    bcol[ni] = rbf(eL[2048 + col]);
#pragma unroll
    for (int r = 0; r < 8; ++r) lbc[ni][r] = eL[1024 + r * 128 + col];
  }
  const int rbase = wm * 64 + (lane >> 4) * 4;
#pragma unroll
  for (int mi = 0; mi < 4; ++mi) {
#pragma unroll
    for (int j = 0; j < 4; ++j) {
      const int row = rbase + mi * 16 + j;
      float hrow[8];
#pragma unroll
      for (int r = 0; r < 8; ++r) hrow[r] = eL[row * 8 + r];
#pragma unroll
      for (int ni = 0; ni < 4; ++ni) {
        const int col = wn * 64 + ni * 16 + fr;
        float v = rbf(acc[mi][ni][j]);       // einsum output rounded to bf16
        v = rbf(v + bcol[ni]);               // + bias in bf16
        float d = 0.f;
#pragma unroll
        for (int r = 0; r < 8; ++r) d += hrow[r] * lbc[ni][r];
        out[(size_t)(m0 + row) * D_OUT + n0 + col] = v + SCALING * d;
      }
    }
  }
}

// ---------------------------------------------------------------------------
extern "C" void kernel_launch(void* const* d_in, const int* in_sizes, int n_in,
                              void* d_out, int out_size, void* d_ws, size_t ws_size,
                              hipStream_t stream) {
  (void)in_sizes; (void)n_in; (void)out_size; (void)ws_size;
  const float* x     = (const float*)d_in[0];
  const int*   qw    = (const int*)d_in[1];     // integer input -> int32 per harness contract
  const float* scale = (const float*)d_in[2];
  const float* bias  = (const float*)d_in[3];
  const float* la    = (const float*)d_in[4];
  const float* lb    = (const float*)d_in[5];
  float* out = (float*)d_out;

  char* ws = (char*)d_ws;
  unsigned short* Wt = (unsigned short*)ws;                          // 33,554,432 B
  unsigned short* xb = (unsigned short*)(ws + 33554432);             // 67,108,864 B
  float* hidden      = (float*)(ws + 33554432 + 67108864);           //    262,144 B

  k_dequant<<<dim3(D_IN / 64, D_OUT / 64), 256, 0, stream>>>(qw, scale, Wt);
  k_cast_hidden<<<M_ROWS / 16, 256, 0, stream>>>(x, la, xb, hidden);
  k_gemm<<<(M_ROWS / TM) * (D_OUT / TN), 256, 0, stream>>>(xb, Wt, bias, hidden, lb, out);
}